// Round 1
// 1281.194 us; speedup vs baseline: 1.2216x; 1.2216x over previous
//
#include <hip/hip_runtime.h>
#include <hip/hip_bf16.h>

using bf16 = __hip_bfloat16;
typedef __attribute__((ext_vector_type(8))) short short8;
typedef __attribute__((ext_vector_type(4))) float float4v;

constexpr int NTOK = 131072;  // 2*256*256

// ---------------- workspace layout (bytes) ----------------
constexpr size_t OFF_Y    = 0;           // bf16 [2][65536][192]  50,331,648
constexpr size_t OFF_T1   = 50331648;    // f32  [131072][24]     12,582,912
constexpr size_t OFF_T2   = 62914560;    // f32  [131072][24]     12,582,912
constexpr size_t OFF_S0   = 75497472;    // f32  [2][192]
constexpr size_t OFF_SG   = 75499008;    // f32  [2][192]
constexpr size_t OFF_WQKV = 75500544;    // bf16 [576][192]       221,184
constexpr size_t OFF_WPRJ = 75721728;    // bf16 [192][192]        73,728
constexpr size_t OFF_WFC1 = 75795456;    // bf16 [768][192]       294,912
constexpr size_t OFF_WFC2 = 76090368;    // bf16 [192][768]       294,912
constexpr size_t OFF_C1WB = 76385280;    // bf16 [32][192]         12,288 (rows 24..31 zero)
constexpr size_t WS_NEEDED = 76397568;

__device__ __forceinline__ int region256(int t) { return t < 248 ? 0 : (t < 252 ? 1 : 2); }

__device__ __forceinline__ short8 lds8(const bf16* p) {
  return *reinterpret_cast<const short8*>(p);
}
__device__ __forceinline__ short8 glb8(const bf16* p) {
  return *reinterpret_cast<const short8*>(p);
}

// ---------------- fp32 -> bf16 weight convert ----------------
__global__ __launch_bounds__(256) void k_f2b(const float* __restrict__ s, bf16* __restrict__ d, int n) {
  int i = blockIdx.x * 256 + threadIdx.x;
  if (i < n) d[i] = __float2bfloat16(s[i]);
}

// ---------------- LCE conv3x3 24->24, LDS-tiled ----------------
__global__ __launch_bounds__(256) void k_lce2t(const float* __restrict__ t1, const float* __restrict__ w,
                                               const float* __restrict__ bia, float* __restrict__ t2) {
  __shared__ float halo[18 * 18 * 25];
  __shared__ float wlds[5184];
  int bid = blockIdx.x;  // 512 = 2 * 16 * 16
  int b = bid >> 8;
  int rem = bid & 255;
  int ty0 = ((rem >> 4) & 15) * 16, tx0 = (rem & 15) * 16;
  for (int idx = threadIdx.x; idx < 5184; idx += 256) wlds[idx] = w[idx];
  for (int idx = threadIdx.x; idx < 18 * 18 * 24; idx += 256) {
    int ch = idx % 24;
    int pp = idx / 24;
    int hy = pp / 18, hx = pp - hy * 18;
    int gy = ty0 + hy - 1, gx = tx0 + hx - 1;
    float v = 0.f;
    if (gy >= 0 && gy < 256 && gx >= 0 && gx < 256)
      v = t1[((size_t)(b << 16) + (gy << 8) + gx) * 24 + ch];
    halo[pp * 25 + ch] = v;
  }
  __syncthreads();
  int py = threadIdx.x >> 4, px = threadIdx.x & 15;
  float acc[24];
#pragma unroll
  for (int ro = 0; ro < 24; ++ro) acc[ro] = bia[ro];
  for (int ky = 0; ky < 3; ++ky) {
    for (int kx = 0; kx < 3; ++kx) {
      int base = ((py + ky) * 18 + px + kx) * 25;
      float inb[24];
#pragma unroll
      for (int ri = 0; ri < 24; ++ri) inb[ri] = halo[base + ri];
      int wo = ky * 3 + kx;
#pragma unroll
      for (int ro = 0; ro < 24; ++ro) {
        float a = acc[ro];
#pragma unroll
        for (int ri = 0; ri < 24; ++ri) a += inb[ri] * wlds[ro * 216 + ri * 9 + wo];
        acc[ro] = a;
      }
    }
  }
  size_t pix = (size_t)(b << 16) + ((ty0 + py) << 8) + tx0 + px;
#pragma unroll
  for (int ro = 0; ro < 24; ++ro) t2[pix * 24 + ro] = acc[ro];
}

// ---------------- LCE conv1x1 24->192 + LeakyReLU -> y (bf16) ----------------
__global__ __launch_bounds__(256) void k_lce3(const float* __restrict__ t2, const float* __restrict__ w,
                                              const float* __restrict__ bia, bf16* __restrict__ y) {
  size_t tid = (size_t)blockIdx.x * 256 + threadIdx.x;
  int c = (int)(tid % 192);
  size_t pix = tid / 192;
  const float* ir = t2 + pix * 24;
  const float* wr = w + c * 24;
  float acc = bia[c];
  for (int ri = 0; ri < 24; ++ri) acc += ir[ri] * wr[ri];
  if (acc < 0.f) acc *= 0.2f;
  y[tid] = __float2bfloat16(acc);
}

// ---------------- global avg pool partial sums ----------------
__global__ __launch_bounds__(192) void k_pool(const bf16* __restrict__ y, float* __restrict__ s0) {
  int b = blockIdx.x >> 10;
  int chunk = blockIdx.x & 1023;
  int c = threadIdx.x;
  size_t base = ((size_t)b * 65536 + chunk * 64) * 192;
  float acc = 0.f;
  for (int p = 0; p < 64; ++p) acc += __bfloat162float(y[base + (size_t)p * 192 + c]);
  atomicAdd(&s0[b * 192 + c], acc);
}

// ---------------- SE gate ----------------
__global__ __launch_bounds__(256) void k_se(const float* __restrict__ s0, const float* __restrict__ w1,
                                            const float* __restrict__ w2, float* __restrict__ sg) {
  __shared__ float mean[192];
  __shared__ float t[24];
  int b = blockIdx.x;
  int tid = threadIdx.x;
  if (tid < 192) mean[tid] = s0[b * 192 + tid] * (1.f / 65536.f);
  __syncthreads();
  if (tid < 24) {
    float a = 0.f;
    for (int c = 0; c < 192; ++c) a += mean[c] * w1[tid * 192 + c];
    t[tid] = fmaxf(a, 0.f);
  }
  __syncthreads();
  if (tid < 192) {
    float a = 0.f;
    for (int r = 0; r < 24; ++r) a += t[r] * w2[tid * 24 + r];
    sg[b * 192 + tid] = 1.f / (1.f + expf(-a));
  }
}

// ---------------- one-barrier fused attention (+ LCE conv1) ----------------
// 2048 blocks (one per window), 256 threads, wave w owns rows 16w..16w+15.
// LDS trimmed to 81,920 B = exactly 2 blocks/CU (was 88,064 -> 1 block/CU,
// OccupancyPercent 12%, latency-bound). Padding replaced by XOR swizzle
// byte ^= ((row&7)<<4): conflict-free (8 lane-dwords/bank) on all b128
// fragment reads; write/read use identical mapping so it is layout-only.
// Layout (byte offsets in dynamic LDS):
//   XW  [64][192] bf16 @ 0       stride 384B   (LN rows; later O rows, per-wave)
//   KL  [64][192] bf16 @ 24576   stride 384B   (K all heads [tok][h*32+d])
//   VT  [192][64] bf16 @ 49152   stride 128B   (V^T [h*32+d][tok])
//   PS  [64][64]  bf16 @ 73728   stride 128B   (per-wave Q/P scratch)
constexpr int SMEM_ATTN2 = 81920;

__device__ __forceinline__ int xw_b(int r, int c) { return (r * 384 + c * 2) ^ ((r & 7) << 4); }
__device__ __forceinline__ int kl_b(int r, int c) { return (24576 + r * 384 + c * 2) ^ ((r & 7) << 4); }
__device__ __forceinline__ int vt_b(int r, int c) { return (49152 + r * 128 + c * 2) ^ ((r & 7) << 4); }
__device__ __forceinline__ int ps_b(int r, int c) { return (73728 + r * 128 + c * 2) ^ ((r & 7) << 4); }

__device__ __forceinline__ short8 lds8o(const char* sm, int byteoff) {
  return *reinterpret_cast<const short8*>(sm + byteoff);
}
__device__ __forceinline__ void st16(char* sm, int byteoff, bf16 v) {
  *reinterpret_cast<bf16*>(sm + byteoff) = v;
}

__global__ __launch_bounds__(256, 2) void k_attn2(const float* __restrict__ x, const float* __restrict__ g,
                                                  const float* __restrict__ bb, const bf16* __restrict__ wq,
                                                  const float* __restrict__ qkvb, const float* __restrict__ rpb,
                                                  const bf16* __restrict__ wp, const float* __restrict__ projb,
                                                  const bf16* __restrict__ c1wb, const float* __restrict__ c1b,
                                                  float* __restrict__ t1, float* __restrict__ x1out) {
  extern __shared__ char sm[];

  int win = blockIdx.x;
  int b = win >> 10;
  int wrem = win & 1023;
  int wh = wrem >> 5, ww = wrem & 31;
  int tid = threadIdx.x;
  int wave = tid >> 6, lane = tid & 63;
  int colB = lane & 15, grp = lane >> 4;
  const float scale = 0.17677669529663687f;  // 1/sqrt(32)

  // ---- Phase 1: LN over this wave's 16 tokens (gather with roll -4)
  for (int t = 0; t < 16; ++t) {
    int tok = wave * 16 + t;
    int i = tok >> 3, j = tok & 7;
    int hp = (wh * 8 + i + 4) & 255;
    int wpp = (ww * 8 + j + 4) & 255;
    const float* xr = x + (((size_t)b << 16) + (hp << 8) + wpp) * 192;
    float v0 = xr[lane], v1 = xr[lane + 64], v2 = xr[lane + 128];
    float s = v0 + v1 + v2;
    for (int o = 32; o > 0; o >>= 1) s += __shfl_down(s, o);
    s = __shfl(s, 0);
    float m = s * (1.f / 192.f);
    float d0 = v0 - m, d1 = v1 - m, d2 = v2 - m;
    float q = d0 * d0 + d1 * d1 + d2 * d2;
    for (int o = 32; o > 0; o >>= 1) q += __shfl_down(q, o);
    q = __shfl(q, 0);
    float inv = rsqrtf(q * (1.f / 192.f) + 1e-5f);
    st16(sm, xw_b(tok, lane),       __float2bfloat16(d0 * inv * g[lane]       + bb[lane]));
    st16(sm, xw_b(tok, lane + 64),  __float2bfloat16(d1 * inv * g[lane + 64]  + bb[lane + 64]));
    st16(sm, xw_b(tok, lane + 128), __float2bfloat16(d2 * inv * g[lane + 128] + bb[lane + 128]));
  }

  // A-fragments of LN rows (same-wave LDS write->read, DS pipe in-order)
  short8 axw[6];
#pragma unroll
  for (int kk = 0; kk < 6; ++kk) axw[kk] = lds8o(sm, xw_b(wave * 16 + colB, kk * 32 + 8 * grp));

  // ---- Phase 2: QKV GEMM + conv1, B-fragments straight from global bf16 weights
  float qreg[48];  // Q C-layout: qreg[nt*4+r], cols nt*16+colB
#pragma unroll
  for (int gq = 0; gq < 4; ++gq) {  // Q: nt 0..11
    float4v acc[3] = {{0,0,0,0},{0,0,0,0},{0,0,0,0}};
#pragma unroll
    for (int kk = 0; kk < 6; ++kk) {
#pragma unroll
      for (int j = 0; j < 3; ++j) {
        int col = (gq * 3 + j) * 16 + colB;
        acc[j] = __builtin_amdgcn_mfma_f32_16x16x32_bf16(axw[kk], glb8(wq + (size_t)col * 192 + kk * 32 + 8 * grp), acc[j], 0, 0, 0);
      }
    }
#pragma unroll
    for (int j = 0; j < 3; ++j) {
      int nt = gq * 3 + j;
      float bias = qkvb[nt * 16 + colB];
#pragma unroll
      for (int r = 0; r < 4; ++r) qreg[nt * 4 + r] = (acc[j][r] + bias) * scale;
    }
  }
  for (int gk = 4; gk < 8; ++gk) {  // K: nt 12..23
    float4v acc[3] = {{0,0,0,0},{0,0,0,0},{0,0,0,0}};
#pragma unroll
    for (int kk = 0; kk < 6; ++kk) {
#pragma unroll
      for (int j = 0; j < 3; ++j) {
        int col = (gk * 3 + j) * 16 + colB;
        acc[j] = __builtin_amdgcn_mfma_f32_16x16x32_bf16(axw[kk], glb8(wq + (size_t)col * 192 + kk * 32 + 8 * grp), acc[j], 0, 0, 0);
      }
    }
    for (int j = 0; j < 3; ++j) {
      int col = (gk * 3 + j) * 16 + colB;
      float bias = qkvb[col];
#pragma unroll
      for (int r = 0; r < 4; ++r)
        st16(sm, kl_b(wave * 16 + 4 * grp + r, col - 192), __float2bfloat16(acc[j][r] + bias));
    }
  }
  for (int gv = 8; gv < 12; ++gv) {  // V: nt 24..35 -> transposed into Vt
    float4v acc[3] = {{0,0,0,0},{0,0,0,0},{0,0,0,0}};
#pragma unroll
    for (int kk = 0; kk < 6; ++kk) {
#pragma unroll
      for (int j = 0; j < 3; ++j) {
        int col = (gv * 3 + j) * 16 + colB;
        acc[j] = __builtin_amdgcn_mfma_f32_16x16x32_bf16(axw[kk], glb8(wq + (size_t)col * 192 + kk * 32 + 8 * grp), acc[j], 0, 0, 0);
      }
    }
    for (int j = 0; j < 3; ++j) {
      int col = (gv * 3 + j) * 16 + colB;
      float bias = qkvb[col];
#pragma unroll
      for (int r = 0; r < 4; ++r)
        st16(sm, vt_b(col - 384, wave * 16 + 4 * grp + r), __float2bfloat16(acc[j][r] + bias));
    }
  }
  {  // conv1 (LCE): 2 N-tiles, weights zero-padded to 32 rows
    float4v acc[2] = {{0,0,0,0},{0,0,0,0}};
#pragma unroll
    for (int kk = 0; kk < 6; ++kk) {
#pragma unroll
      for (int j = 0; j < 2; ++j) {
        int row = j * 16 + colB;
        acc[j] = __builtin_amdgcn_mfma_f32_16x16x32_bf16(axw[kk], glb8(c1wb + (size_t)row * 192 + kk * 32 + 8 * grp), acc[j], 0, 0, 0);
      }
    }
#pragma unroll
    for (int j = 0; j < 2; ++j) {
      int ch = j * 16 + colB;
      if (ch < 24) {
        float bias = c1b[ch];
#pragma unroll
        for (int r = 0; r < 4; ++r) {
          int tok = wave * 16 + 4 * grp + r;
          int i = tok >> 3, jj = tok & 7;
          int hp = (wh * 8 + i + 4) & 255;
          int wpp = (ww * 8 + jj + 4) & 255;
          size_t pix = ((size_t)b << 16) + (hp << 8) + wpp;
          t1[pix * 24 + ch] = acc[j][r] + bias;
        }
      }
    }
  }
  __syncthreads();  // THE barrier: K/Vt now visible to all waves

  // row constants for bias/mask
  int l1r[4], i1r[4], j1r[4];
#pragma unroll
  for (int r = 0; r < 4; ++r) {
    int n = wave * 16 + 4 * grp + r;
    i1r[r] = n >> 3; j1r[r] = n & 7;
    l1r[r] = region256(wh * 8 + i1r[r]) * 3 + region256(ww * 8 + j1r[r]);
  }

  // ---- Phase 3: per-head attention (no barriers; PS is per-wave private)
  for (int h = 0; h < 6; ++h) {
    // Q tile -> scratch -> A-frag
#pragma unroll
    for (int t = 0; t < 2; ++t)
#pragma unroll
      for (int r = 0; r < 4; ++r)
        st16(sm, ps_b(wave * 16 + 4 * grp + r, t * 16 + colB), __float2bfloat16(qreg[(h * 2 + t) * 4 + r]));
    short8 aq = lds8o(sm, ps_b(wave * 16 + colB, 8 * grp));

    float4v s[4];
#pragma unroll
    for (int nt = 0; nt < 4; ++nt) {
      short8 bk = lds8o(sm, kl_b(nt * 16 + colB, h * 32 + 8 * grp));
      float4v z = {0, 0, 0, 0};
      s[nt] = __builtin_amdgcn_mfma_f32_16x16x32_bf16(aq, bk, z, 0, 0, 0);
    }
#pragma unroll
    for (int nt = 0; nt < 4; ++nt) {
      int m = nt * 16 + colB;
      int i2 = m >> 3, j2 = m & 7;
      int l2 = region256(wh * 8 + i2) * 3 + region256(ww * 8 + j2);
#pragma unroll
      for (int r = 0; r < 4; ++r) {
        float bias = rpb[((i1r[r] - i2 + 7) * 15 + (j1r[r] - j2 + 7)) * 6 + h];
        s[nt][r] += bias + (l1r[r] != l2 ? -100.f : 0.f);
      }
    }
#pragma unroll
    for (int r = 0; r < 4; ++r) {
      float mx = fmaxf(fmaxf(s[0][r], s[1][r]), fmaxf(s[2][r], s[3][r]));
      mx = fmaxf(mx, __shfl_xor(mx, 1));
      mx = fmaxf(mx, __shfl_xor(mx, 2));
      mx = fmaxf(mx, __shfl_xor(mx, 4));
      mx = fmaxf(mx, __shfl_xor(mx, 8));
      float e0 = __expf(s[0][r] - mx), e1 = __expf(s[1][r] - mx);
      float e2 = __expf(s[2][r] - mx), e3 = __expf(s[3][r] - mx);
      float sum = e0 + e1 + e2 + e3;
      sum += __shfl_xor(sum, 1);
      sum += __shfl_xor(sum, 2);
      sum += __shfl_xor(sum, 4);
      sum += __shfl_xor(sum, 8);
      float inv = 1.f / sum;
      int row = wave * 16 + 4 * grp + r;
      st16(sm, ps_b(row, 0 * 16 + colB), __float2bfloat16(e0 * inv));
      st16(sm, ps_b(row, 1 * 16 + colB), __float2bfloat16(e1 * inv));
      st16(sm, ps_b(row, 2 * 16 + colB), __float2bfloat16(e2 * inv));
      st16(sm, ps_b(row, 3 * 16 + colB), __float2bfloat16(e3 * inv));
    }
    short8 ap0 = lds8o(sm, ps_b(wave * 16 + colB, 0 * 32 + 8 * grp));
    short8 ap1 = lds8o(sm, ps_b(wave * 16 + colB, 1 * 32 + 8 * grp));

    float4v o0 = {0, 0, 0, 0}, o1 = {0, 0, 0, 0};
    o0 = __builtin_amdgcn_mfma_f32_16x16x32_bf16(ap0, lds8o(sm, vt_b(h * 32 + colB, 8 * grp)), o0, 0, 0, 0);
    o0 = __builtin_amdgcn_mfma_f32_16x16x32_bf16(ap1, lds8o(sm, vt_b(h * 32 + colB, 32 + 8 * grp)), o0, 0, 0, 0);
    o1 = __builtin_amdgcn_mfma_f32_16x16x32_bf16(ap0, lds8o(sm, vt_b(h * 32 + 16 + colB, 8 * grp)), o1, 0, 0, 0);
    o1 = __builtin_amdgcn_mfma_f32_16x16x32_bf16(ap1, lds8o(sm, vt_b(h * 32 + 16 + colB, 32 + 8 * grp)), o1, 0, 0, 0);
#pragma unroll
    for (int r = 0; r < 4; ++r) {
      int row = wave * 16 + 4 * grp + r;
      st16(sm, xw_b(row, h * 32 + colB),      __float2bfloat16(o0[r]));  // XW now = O (per-wave rows)
      st16(sm, xw_b(row, h * 32 + 16 + colB), __float2bfloat16(o1[r]));
    }
  }

  // ---- Phase 4: proj + reverse-shift scatter + residual
  short8 ao[6];
#pragma unroll
  for (int kk = 0; kk < 6; ++kk) ao[kk] = lds8o(sm, xw_b(wave * 16 + colB, kk * 32 + 8 * grp));
  for (int gp = 0; gp < 4; ++gp) {
    float4v acc[3] = {{0,0,0,0},{0,0,0,0},{0,0,0,0}};
#pragma unroll
    for (int kk = 0; kk < 6; ++kk) {
#pragma unroll
      for (int j = 0; j < 3; ++j) {
        int col = (gp * 3 + j) * 16 + colB;
        acc[j] = __builtin_amdgcn_mfma_f32_16x16x32_bf16(ao[kk], glb8(wp + (size_t)col * 192 + kk * 32 + 8 * grp), acc[j], 0, 0, 0);
      }
    }
#pragma unroll
    for (int j = 0; j < 3; ++j) {
      int col = (gp * 3 + j) * 16 + colB;
      float bias = projb[col];
#pragma unroll
      for (int r = 0; r < 4; ++r) {
        int n = wave * 16 + 4 * grp + r;
        int i = n >> 3, jj = n & 7;
        int hd2 = (wh * 8 + i + 4) & 255;
        int wd2 = (ww * 8 + jj + 4) & 255;
        size_t p = (((size_t)b << 16) + (hd2 << 8) + wd2) * 192 + col;
        x1out[p] = x[p] + acc[j][r] + bias;
      }
    }
  }
}

// ---------------- MFMA MLP: LN2 + fc1 + GELU + fc2 + residual (in-place) ----------------
__global__ __launch_bounds__(256, 2) void k_mlp_mfma(float* __restrict__ x1, const float* __restrict__ g,
                                                     const float* __restrict__ bb, const bf16* __restrict__ w1,
                                                     const float* __restrict__ b1, const bf16* __restrict__ w2,
                                                     const float* __restrict__ b2) {
  __shared__ bf16 xl[32][200];
  __shared__ bf16 hh[32][776];
  int tid = threadIdx.x;
  int wave = tid >> 6, lane = tid & 63;
  int colB = lane & 15, grp = lane >> 4;
  size_t tokbase = (size_t)blockIdx.x * 32;

  for (int t = wave; t < 32; t += 4) {
    const float* xr = x1 + (tokbase + t) * 192;
    float v0 = xr[lane], v1 = xr[lane + 64], v2 = xr[lane + 128];
    float s = v0 + v1 + v2;
    for (int o = 32; o > 0; o >>= 1) s += __shfl_down(s, o);
    s = __shfl(s, 0);
    float m = s * (1.f / 192.f);
    float d0 = v0 - m, d1 = v1 - m, d2 = v2 - m;
    float qq = d0 * d0 + d1 * d1 + d2 * d2;
    for (int o = 32; o > 0; o >>= 1) qq += __shfl_down(qq, o);
    qq = __shfl(qq, 0);
    float inv = rsqrtf(qq * (1.f / 192.f) + 1e-5f);
    xl[t][lane]       = __float2bfloat16(d0 * inv * g[lane]       + bb[lane]);
    xl[t][lane + 64]  = __float2bfloat16(d1 * inv * g[lane + 64]  + bb[lane + 64]);
    xl[t][lane + 128] = __float2bfloat16(d2 * inv * g[lane + 128] + bb[lane + 128]);
  }
  __syncthreads();

  short8 a1f[6][2];
#pragma unroll
  for (int kk = 0; kk < 6; ++kk) {
    a1f[kk][0] = lds8(&xl[colB][kk * 32 + 8 * grp]);
    a1f[kk][1] = lds8(&xl[16 + colB][kk * 32 + 8 * grp]);
  }
  for (int nn = 0; nn < 12; ++nn) {
    int nt = wave * 12 + nn;
    float4v c0 = {0, 0, 0, 0}, c1 = {0, 0, 0, 0};
#pragma unroll
    for (int kk = 0; kk < 6; ++kk) {
      short8 bw = glb8(w1 + (size_t)(nt * 16 + colB) * 192 + kk * 32 + 8 * grp);
      c0 = __builtin_amdgcn_mfma_f32_16x16x32_bf16(a1f[kk][0], bw, c0, 0, 0, 0);
      c1 = __builtin_amdgcn_mfma_f32_16x16x32_bf16(a1f[kk][1], bw, c1, 0, 0, 0);
    }
    int col = nt * 16 + colB;
    float bias = b1[col];
#pragma unroll
    for (int r = 0; r < 4; ++r) {
      float v0 = c0[r] + bias;
      float v1 = c1[r] + bias;
      v0 = v0 * 0.5f * (1.f + erff(v0 * 0.70710678118654752f));
      v1 = v1 * 0.5f * (1.f + erff(v1 * 0.70710678118654752f));
      hh[4 * grp + r][col] = __float2bfloat16(v0);
      hh[16 + 4 * grp + r][col] = __float2bfloat16(v1);
    }
  }
  __syncthreads();

  float4v d0[3] = {{0,0,0,0},{0,0,0,0},{0,0,0,0}};
  float4v d1[3] = {{0,0,0,0},{0,0,0,0},{0,0,0,0}};
  int ntb = wave * 3;
  for (int kk = 0; kk < 24; ++kk) {
    int ko = kk * 32 + 8 * grp;
    short8 h0 = lds8(&hh[colB][ko]);
    short8 h1 = lds8(&hh[16 + colB][ko]);
#pragma unroll
    for (int j = 0; j < 3; ++j) {
      short8 bw = glb8(w2 + (size_t)((ntb + j) * 16 + colB) * 768 + ko);
      d0[j] = __builtin_amdgcn_mfma_f32_16x16x32_bf16(h0, bw, d0[j], 0, 0, 0);
      d1[j] = __builtin_amdgcn_mfma_f32_16x16x32_bf16(h1, bw, d1[j], 0, 0, 0);
    }
  }
#pragma unroll
  for (int j = 0; j < 3; ++j) {
    int col = (ntb + j) * 16 + colB;
    float bias = b2[col];
#pragma unroll
    for (int r = 0; r < 4; ++r) {
      size_t p0 = (tokbase + 4 * grp + r) * 192 + col;
      size_t p1 = (tokbase + 16 + 4 * grp + r) * 192 + col;
      x1[p0] += d0[j][r] + bias;
      x1[p1] += d1[j][r] + bias;
    }
  }
}

// ---------------- out += y * gate ----------------
__global__ __launch_bounds__(256) void k_final(float* __restrict__ out, const bf16* __restrict__ y,
                                               const float* __restrict__ sg) {
  size_t i = (size_t)blockIdx.x * 256 + threadIdx.x;
  int c = (int)(i % 192);
  size_t pix = i / 192;
  int b = (int)(pix >> 16);
  out[i] += __bfloat162float(y[i]) * sg[b * 192 + c];
}

extern "C" void kernel_launch(void* const* d_in, const int* in_sizes, int n_in,
                              void* d_out, int out_size, void* d_ws, size_t ws_size,
                              hipStream_t stream) {
  const float* x     = (const float*)d_in[0];
  const float* n1g   = (const float*)d_in[1];
  const float* n1b   = (const float*)d_in[2];
  const float* qkvw  = (const float*)d_in[3];
  const float* qkvb  = (const float*)d_in[4];
  const float* rpb   = (const float*)d_in[5];
  const float* projw = (const float*)d_in[6];
  const float* projb = (const float*)d_in[7];
  const float* n2g   = (const float*)d_in[8];
  const float* n2b   = (const float*)d_in[9];
  const float* w1    = (const float*)d_in[10];
  const float* b1    = (const float*)d_in[11];
  const float* w2    = (const float*)d_in[12];
  const float* b2    = (const float*)d_in[13];
  const float* c1w   = (const float*)d_in[14];
  const float* c1b   = (const float*)d_in[15];
  const float* c2w   = (const float*)d_in[16];
  const float* c2b   = (const float*)d_in[17];
  const float* c3w   = (const float*)d_in[18];
  const float* c3b   = (const float*)d_in[19];
  const float* sfc1  = (const float*)d_in[20];
  const float* sfc2  = (const float*)d_in[21];
  float* out = (float*)d_out;

  if (ws_size < WS_NEEDED) return;

  char* ws = (char*)d_ws;
  bf16*  ybf  = (bf16*)(ws + OFF_Y);
  float* t1   = (float*)(ws + OFF_T1);
  float* t2   = (float*)(ws + OFF_T2);
  float* s0   = (float*)(ws + OFF_S0);
  float* sg   = (float*)(ws + OFF_SG);
  bf16*  wqkv = (bf16*)(ws + OFF_WQKV);
  bf16*  wprj = (bf16*)(ws + OFF_WPRJ);
  bf16*  wfc1 = (bf16*)(ws + OFF_WFC1);
  bf16*  wfc2 = (bf16*)(ws + OFF_WFC2);
  bf16*  c1wb = (bf16*)(ws + OFF_C1WB);

  hipFuncSetAttribute((const void*)k_attn2, hipFuncAttributeMaxDynamicSharedMemorySize, SMEM_ATTN2);

  hipMemsetAsync(s0, 0, 384 * sizeof(float), stream);
  hipMemsetAsync((char*)c1wb + 24 * 192 * sizeof(bf16), 0, 8 * 192 * sizeof(bf16), stream);

  k_f2b<<<(110592 + 255) / 256, 256, 0, stream>>>(qkvw, wqkv, 110592);
  k_f2b<<<(36864 + 255) / 256, 256, 0, stream>>>(projw, wprj, 36864);
  k_f2b<<<(147456 + 255) / 256, 256, 0, stream>>>(w1, wfc1, 147456);
  k_f2b<<<(147456 + 255) / 256, 256, 0, stream>>>(w2, wfc2, 147456);
  k_f2b<<<(4608 + 255) / 256, 256, 0, stream>>>(c1w, c1wb, 4608);

  // fused attention + LN1 + LCE conv1 (t1), writes x1 into d_out
  k_attn2<<<2048, 256, SMEM_ATTN2, stream>>>(x, n1g, n1b, wqkv, qkvb, rpb, wprj, projb,
                                             c1wb, c1b, t1, out);
  // LCE tail
  k_lce2t<<<512, 256, 0, stream>>>(t1, c2w, c2b, t2);
  k_lce3<<<(NTOK * 192) / 256, 256, 0, stream>>>(t2, c3w, c3b, ybf);
  k_pool<<<2048, 192, 0, stream>>>(ybf, s0);
  k_se<<<2, 256, 0, stream>>>(s0, sfc1, sfc2, sg);
  // MLP in-place on d_out
  k_mlp_mfma<<<NTOK / 32, 256, 0, stream>>>(out, n2g, n2b, wfc1, b1, wfc2, b2);
  // final: out = x2 + y * gate
  k_final<<<(NTOK * 192) / 256, 256, 0, stream>>>(out, ybf, sg);
}